// Round 14
// baseline (178.384 us; speedup 1.0000x reference)
//
#include <hip/hip_runtime.h>

typedef unsigned short u16;
typedef unsigned int   u32;
typedef __bf16  bf16x8 __attribute__((ext_vector_type(8)));
typedef float   f32x4  __attribute__((ext_vector_type(4)));
typedef float   f32x16 __attribute__((ext_vector_type(16)));
typedef u16     u16x4  __attribute__((ext_vector_type(4)));
typedef u16     u16x8  __attribute__((ext_vector_type(8)));
typedef u32     u32x4  __attribute__((ext_vector_type(4)));

#define D_MODEL 1024
#define N_HEADS 16
#define HEAD_DIM 64
#define BATCH 4
#define SEQ 2048
#define MROWS (BATCH*SEQ)

__device__ __forceinline__ u16 f2bf(float f){
  unsigned u = __builtin_bit_cast(unsigned, f);
  u += 0x7fffu + ((u >> 16) & 1u);
  return (u16)(u >> 16);
}
__device__ __forceinline__ float bf2f(u16 h){
  unsigned u = ((unsigned)h) << 16;
  return __builtin_bit_cast(float, u);
}
__device__ __forceinline__ u32 cvtpk(float a, float b){
  u32 r; asm("v_cvt_pk_bf16_f32 %0, %1, %2" : "=v"(r) : "v"(a), "v"(b)); return r;
}
__device__ __forceinline__ void gload_lds16(const u16* g, u16* l){
  __builtin_amdgcn_global_load_lds((const __attribute__((address_space(1))) void*)g,
                                   (__attribute__((address_space(3))) void*)l, 16, 0, 0);
}
#define MFMA16(a,b,c) __builtin_amdgcn_mfma_f32_16x16x32_bf16((a),(b),(c),0,0,0)

// ---------- fused prep: x->bf16 | W transpose (+q/k head-perm) | RoPE table ----------
__global__ void k_prep(const float* __restrict__ x, const float* __restrict__ Wq,
                       const float* __restrict__ Wk, const float* __restrict__ Wv,
                       const float* __restrict__ Wo, const int* __restrict__ pos,
                       u16* __restrict__ xb, u16* __restrict__ wt, float2* __restrict__ tab){
  __shared__ float t[32][33];
  const int blk = blockIdx.x, tid = threadIdx.x;
  if (blk < 8192){                              // ---- x fp32 -> bf16 (float4/thread)
    int i = blk * 256 + tid;
    float4 v = reinterpret_cast<const float4*>(x)[i];
    u16x4 o;
    o.x = f2bf(v.x); o.y = f2bf(v.y); o.z = f2bf(v.z); o.w = f2bf(v.w);
    *reinterpret_cast<u16x4*>(xb + (size_t)i * 4) = o;
  } else if (blk < 12288){                      // ---- W [k][n] -> Wt [n][k] bf16
    int idx = blk - 8192;
    int z = idx >> 10;
    int n0 = (idx & 31) * 32, k0 = ((idx >> 5) & 31) * 32;
    const float* W = (z==0)?Wq:(z==1)?Wk:(z==2)?Wv:Wo;
    u16* O = wt + (size_t)z * (D_MODEL*(size_t)D_MODEL);
    int tx = tid & 31, ty = tid >> 5;
    #pragma unroll
    for (int i = ty; i < 32; i += 8) t[i][tx] = W[(size_t)(k0+i)*D_MODEL + n0 + tx];
    __syncthreads();
    #pragma unroll
    for (int i = ty; i < 32; i += 8){
      int n = n0 + i;
      int np = n;
      if (z < 2){ int d = n & 63; np = (n & ~63) | ((d & 1) << 5) | (d >> 1); }
      O[(size_t)np*D_MODEL + k0 + tx] = f2bf(t[tx][i]);
    }
  } else {                                      // ---- RoPE cos/sin table
    int i = (blk - 12288) * 256 + tid;          // SEQ*32 entries
    int s = i >> 5, f = i & 31;
    float inv = exp2f(-(float)f * (13.287712379549449f / 32.0f));
    float a = (float)pos[s] * inv;
    float sn, cs;
    sincosf(a, &sn, &cs);
    tab[i] = make_float2(cs, sn);
  }
}

// ---------- QKV GEMM: 128x256 tile, BK=32, 8 waves, 3-buffer counted-vmcnt,
// ---------- T2-swizzled LDS, fine phase interleave + setprio (r13 exact) ----------
__global__ __launch_bounds__(512, 4) void k_gqkv(const u16* __restrict__ A, const u16* __restrict__ Bt,
                                                 const float2* __restrict__ tab,
                                                 u16* __restrict__ qout, u16* __restrict__ kout,
                                                 u16* __restrict__ vout){
  __shared__ u16 sh[3*12288];   // 72 KB: per buf: A 128x32 @0 (4096 u16), B 256x32 @4096 (8192 u16)
  const int tid = threadIdx.x, lane = tid & 63, w = tid >> 6;
  const int lr = lane & 15, lg = lane >> 4;
  const int m0 = blockIdx.x * 128, n0 = blockIdx.y * 256;   // m fast (r9 order)
  const int wm = w >> 2, wn = w & 3;
  const int ra = tid >> 2;
  const int sca = ((tid & 3) ^ ((ra >> 1) & 3)) << 3;
  const u16* gA  = A  + (size_t)(m0 + ra)*1024 + sca;
  const u16* gB0 = Bt + (size_t)(n0 + ra)*1024 + sca;
  const int rb1 = 128 + ra;
  const u16* gB1 = Bt + (size_t)(n0 + rb1)*1024 + (((tid & 3) ^ ((rb1 >> 1) & 3)) << 3);
  const int dA  = w*512;
  const int dB0 = 4096 + w*512;
  const int dB1 = 8192 + w*512;
  int aoff[4], boff[4];
  #pragma unroll
  for (int mi = 0; mi < 4; ++mi){ int r_ = wm*64 + mi*16 + lr; aoff[mi] = r_*32 + ((lg ^ ((r_>>1)&3)) << 3); }
  #pragma unroll
  for (int ni = 0; ni < 4; ++ni){ int r_ = wn*64 + ni*16 + lr; boff[ni] = 4096 + r_*32 + ((lg ^ ((r_>>1)&3)) << 3); }

  f32x4 acc[4][4] = {};
#define SA_(base, t)  gload_lds16(gA  + (size_t)(t)*32, sh + (base) + dA)
#define SB0_(base, t) gload_lds16(gB0 + (size_t)(t)*32, sh + (base) + dB0)
#define SB1_(base, t) gload_lds16(gB1 + (size_t)(t)*32, sh + (base) + dB1)
  SA_(0,0); SB0_(0,0); SB1_(0,0);
  SA_(12288,1); SB0_(12288,1); SB1_(12288,1);
  int b0 = 0, b1 = 12288, b2 = 24576;
  #pragma unroll 1
  for (int t = 0; t < 32; ++t){
    if (t < 31) { asm volatile("s_waitcnt vmcnt(3) lgkmcnt(0)" ::: "memory"); }
    else        { asm volatile("s_waitcnt vmcnt(0) lgkmcnt(0)" ::: "memory"); }
    __builtin_amdgcn_s_barrier();
    __builtin_amdgcn_sched_barrier(0);
    const u16* Sb = sh + b0;
    bf16x8 af0 = *(const bf16x8*)&Sb[aoff[0]];
    bf16x8 af1 = *(const bf16x8*)&Sb[aoff[1]];
    bf16x8 af2 = *(const bf16x8*)&Sb[aoff[2]];
    bf16x8 af3 = *(const bf16x8*)&Sb[aoff[3]];
    bf16x8 vb0 = *(const bf16x8*)&Sb[boff[0]];
    bf16x8 vb1 = *(const bf16x8*)&Sb[boff[1]];
    if (t < 30){ SA_(b2, t+2); }
    __builtin_amdgcn_s_setprio(1);
    acc[0][0] = MFMA16(af0, vb0, acc[0][0]);
    acc[1][0] = MFMA16(af1, vb0, acc[1][0]);
    acc[2][0] = MFMA16(af2, vb0, acc[2][0]);
    acc[3][0] = MFMA16(af3, vb0, acc[3][0]);
    acc[0][1] = MFMA16(af0, vb1, acc[0][1]);
    acc[1][1] = MFMA16(af1, vb1, acc[1][1]);
    acc[2][1] = MFMA16(af2, vb1, acc[2][1]);
    acc[3][1] = MFMA16(af3, vb1, acc[3][1]);
    __builtin_amdgcn_s_setprio(0);
    bf16x8 vb2 = *(const bf16x8*)&Sb[boff[2]];
    bf16x8 vb3 = *(const bf16x8*)&Sb[boff[3]];
    if (t < 30){ SB0_(b2, t+2); SB1_(b2, t+2); }
    __builtin_amdgcn_s_setprio(1);
    acc[0][2] = MFMA16(af0, vb2, acc[0][2]);
    acc[1][2] = MFMA16(af1, vb2, acc[1][2]);
    acc[2][2] = MFMA16(af2, vb2, acc[2][2]);
    acc[3][2] = MFMA16(af3, vb2, acc[3][2]);
    acc[0][3] = MFMA16(af0, vb3, acc[0][3]);
    acc[1][3] = MFMA16(af1, vb3, acc[1][3]);
    acc[2][3] = MFMA16(af2, vb3, acc[2][3]);
    acc[3][3] = MFMA16(af3, vb3, acc[3][3]);
    __builtin_amdgcn_s_setprio(0);
    int tmp = b0; b0 = b1; b1 = b2; b2 = tmp;
  }
#undef SA_
#undef SB0_
#undef SB1_

  const int which = n0 >> 10;                 // 0=q 1=k 2=v
  #pragma unroll
  for (int mi = 0; mi < 4; mi++){
    int row = m0 + wm*64 + mi*16 + lg*4;
    #pragma unroll
    for (int ni = 0; ni < 4; ni++){
      int col = n0 + wn*64 + ni*16 + lr;
      int cm = col & 1023;
      int hh = cm >> 6, d = cm & 63;
      f32x4 vv = acc[mi][ni];
      f32x4 vp = acc[mi][ni ^ 2];             // rope partner (in-lane, permuted layout)
      #pragma unroll
      for (int r = 0; r < 4; r++){
        int rr = row + r;
        int bb = rr >> 11, s = rr & (SEQ-1);
        float val = vv[r];
        if (which < 2){
          float e = (ni < 2) ? val : vp[r];
          float o = (ni < 2) ? vp[r] : val;
          float2 cs = tab[s*32 + ((ni & 1) << 4) + lr];
          float ov = (ni < 2) ? (e*cs.x - o*cs.y) : (e*cs.y + o*cs.x);
          if (which == 0){
            ov *= 0.18033688011112042f;       // 0.125 * log2(e)
            qout[(size_t)rr*1024 + cm] = f2bf(ov);
          } else {
            kout[(((size_t)(bb*N_HEADS + hh))*SEQ + s)*64 + d] = f2bf(ov);
          }
        } else {
          vout[(((size_t)(bb*N_HEADS + hh))*(SEQ/16) + (s >> 4))*1024 + d*16 + (s & 15)] = f2bf(val);
        }
      }
    }
  }
}

// ---------- Wo GEMM: 128x128, BK=32, 4 waves, 3-buffer counted-vmcnt
// ---------- + T2 swizzle + fine interleave + setprio (r13 exact) ----------
__global__ __launch_bounds__(256, 4) void k_gwo(const u16* __restrict__ A, const u16* __restrict__ Bt,
                                                float* __restrict__ fout){
  __shared__ u16 sh[3*8192];                 // 48 KB: per buf A 128x32 @0, B 128x32 @4096
  const int tid = threadIdx.x, lane = tid & 63, w = tid >> 6;
  const int lr = lane & 15, lg = lane >> 4;
  const int m0 = blockIdx.x * 128, n0 = blockIdx.y * 128;   // m fast (r9 order)
  const int wm = w >> 1, wn = w & 1;
  const int ra = w*16 + (lane >> 2);
  const int sc = ((lane & 3) ^ ((ra >> 1) & 3)) << 3;
  const u16* gA0 = A  + (size_t)(m0 + ra)*1024 + sc;
  const u16* gA1 = A  + (size_t)(m0 + 64 + ra)*1024 + sc;
  const u16* gB0 = Bt + (size_t)(n0 + ra)*1024 + sc;
  const u16* gB1 = Bt + (size_t)(n0 + 64 + ra)*1024 + sc;
  int aoff[4], boff[4];
  #pragma unroll
  for (int mi = 0; mi < 4; ++mi){ int r_ = wm*64 + mi*16 + lr; aoff[mi] = r_*32 + ((lg ^ ((r_>>1)&3)) << 3); }
  #pragma unroll
  for (int ni = 0; ni < 4; ++ni){ int r_ = wn*64 + ni*16 + lr; boff[ni] = 4096 + r_*32 + ((lg ^ ((r_>>1)&3)) << 3); }
  f32x4 acc[4][4] = {};
#define SAW(base, t) { gload_lds16(gA0 + (size_t)(t)*32, sh + (base) + w*512); \
                       gload_lds16(gA1 + (size_t)(t)*32, sh + (base) + 2048 + w*512); }
#define SBW(base, t) { gload_lds16(gB0 + (size_t)(t)*32, sh + (base) + 4096 + w*512); \
                       gload_lds16(gB1 + (size_t)(t)*32, sh + (base) + 6144 + w*512); }
  SAW(0,0) SBW(0,0)
  SAW(8192,1) SBW(8192,1)
  int b0 = 0, b1 = 8192, b2 = 16384;
  #pragma unroll 1
  for (int t = 0; t < 32; ++t){
    if (t < 31) { asm volatile("s_waitcnt vmcnt(4) lgkmcnt(0)" ::: "memory"); }
    else        { asm volatile("s_waitcnt vmcnt(0) lgkmcnt(0)" ::: "memory"); }
    __builtin_amdgcn_s_barrier();
    __builtin_amdgcn_sched_barrier(0);
    const u16* Sb = sh + b0;
    bf16x8 af0 = *(const bf16x8*)&Sb[aoff[0]];
    bf16x8 af1 = *(const bf16x8*)&Sb[aoff[1]];
    bf16x8 af2 = *(const bf16x8*)&Sb[aoff[2]];
    bf16x8 af3 = *(const bf16x8*)&Sb[aoff[3]];
    bf16x8 vb0 = *(const bf16x8*)&Sb[boff[0]];
    bf16x8 vb1 = *(const bf16x8*)&Sb[boff[1]];
    if (t < 30){ SAW(b2, t+2) }
    __builtin_amdgcn_s_setprio(1);
    acc[0][0] = MFMA16(af0, vb0, acc[0][0]);
    acc[1][0] = MFMA16(af1, vb0, acc[1][0]);
    acc[2][0] = MFMA16(af2, vb0, acc[2][0]);
    acc[3][0] = MFMA16(af3, vb0, acc[3][0]);
    acc[0][1] = MFMA16(af0, vb1, acc[0][1]);
    acc[1][1] = MFMA16(af1, vb1, acc[1][1]);
    acc[2][1] = MFMA16(af2, vb1, acc[2][1]);
    acc[3][1] = MFMA16(af3, vb1, acc[3][1]);
    __builtin_amdgcn_s_setprio(0);
    bf16x8 vb2 = *(const bf16x8*)&Sb[boff[2]];
    bf16x8 vb3 = *(const bf16x8*)&Sb[boff[3]];
    if (t < 30){ SBW(b2, t+2) }
    __builtin_amdgcn_s_setprio(1);
    acc[0][2] = MFMA16(af0, vb2, acc[0][2]);
    acc[1][2] = MFMA16(af1, vb2, acc[1][2]);
    acc[2][2] = MFMA16(af2, vb2, acc[2][2]);
    acc[3][2] = MFMA16(af3, vb2, acc[3][2]);
    acc[0][3] = MFMA16(af0, vb3, acc[0][3]);
    acc[1][3] = MFMA16(af1, vb3, acc[1][3]);
    acc[2][3] = MFMA16(af2, vb3, acc[2][3]);
    acc[3][3] = MFMA16(af3, vb3, acc[3][3]);
    __builtin_amdgcn_s_setprio(0);
    int tmp = b0; b0 = b1; b1 = b2; b2 = tmp;
  }
#undef SAW
#undef SBW
  #pragma unroll
  for (int mi = 0; mi < 4; mi++){
    int row = m0 + wm*64 + mi*16 + lg*4;
    #pragma unroll
    for (int ni = 0; ni < 4; ni++){
      int col = n0 + wn*64 + ni*16 + lr;
      f32x4 vv = acc[mi][ni];
      #pragma unroll
      for (int r = 0; r < 4; r++)
        fout[(size_t)(row + r)*1024 + col] = vv[r];
    }
  }
}

// ---------- causal flash attention: 4-wave blocks, KVBLK=64 staged, 32-key groups
// ---------- processed sequentially (scoped S regs) -> fits (256,4): 4 blocks/CU,
// ---------- 1024 resident = zero tail. setprio around MFMA clusters (T5).
__global__ __launch_bounds__(256, 4) void k_attn(const u16* __restrict__ q, const u16* __restrict__ k2,
                                                 const u16* __restrict__ v2, u16* __restrict__ ctx){
  __shared__ u16 kv[2][8192];                 // per buf: K 8KB | V 8KB
  const int lane = threadIdx.x & 63, w = threadIdx.x >> 6;
  const int lq = lane & 31, hl = lane >> 5;
  const int B = blockIdx.x;
  const int bh = B & 63, g = 15 - (B >> 6);
  const int b = bh >> 4, h = bh & 15;
  const int qi = 4*g + w;
  const int q0 = qi * 32;
  const int qmax0 = (4*g + 3) * 32;           // block-uniform loop bound
  const u16* kglob = k2 + (size_t)bh*SEQ*64;
  const u16* vglob = v2 + (size_t)bh*(SEQ/16)*1024;

  const u16* qr_ = q + (size_t)(b*SEQ + q0 + lq)*D_MODEL + h*HEAD_DIM + hl*8;
  bf16x8 qf0 = *(const bf16x8*)&qr_[0];
  bf16x8 qf1 = *(const bf16x8*)&qr_[16];
  bf16x8 qf2 = *(const bf16x8*)&qr_[32];
  bf16x8 qf3 = *(const bf16x8*)&qr_[48];
  f32x16 acc0 = {}, acc1 = {};
  float m = -3.0e38f, l = 0.f;

  const int kr_ = (w<<3) + (lane>>3);                 // stage K row in 0..31
  const int kc_ = ((lane&7) ^ (lane>>3)) << 3;        // swizzled source chunk
  auto STAGE = [&](int bf, int jt){
    gload_lds16(kglob + (size_t)(jt      + kr_)*64 + kc_, &kv[bf][w<<9]);
    gload_lds16(kglob + (size_t)(jt + 32 + kr_)*64 + kc_, &kv[bf][2048 + (w<<9)]);
    gload_lds16(vglob + ((size_t)(jt>>4)<<10)        + (w<<9) + (lane<<3), &kv[bf][4096 + (w<<9)]);
    gload_lds16(vglob + ((size_t)((jt+32)>>4)<<10)   + (w<<9) + (lane<<3), &kv[bf][6144 + (w<<9)]);
  };

  // one 32-key group: QK^T -> (mask) -> online softmax -> pack -> PV
  auto GROUP = [&](const char* kb, const char* vb, bool diag){
    f32x16 S = {};
    {
      bf16x8 kf0 = *(const bf16x8*)(kb + lq*128 + (((0+hl) ^ (lq&7))<<4));
      bf16x8 kf1 = *(const bf16x8*)(kb + lq*128 + (((2+hl) ^ (lq&7))<<4));
      bf16x8 kf2 = *(const bf16x8*)(kb + lq*128 + (((4+hl) ^ (lq&7))<<4));
      bf16x8 kf3 = *(const bf16x8*)(kb + lq*128 + (((6+hl) ^ (lq&7))<<4));
      __builtin_amdgcn_s_setprio(1);
      S = __builtin_amdgcn_mfma_f32_32x32x16_bf16(kf0, qf0, S, 0, 0, 0);
      S = __builtin_amdgcn_mfma_f32_32x32x16_bf16(kf1, qf1, S, 0, 0, 0);
      S = __builtin_amdgcn_mfma_f32_32x32x16_bf16(kf2, qf2, S, 0, 0, 0);
      S = __builtin_amdgcn_mfma_f32_32x32x16_bf16(kf3, qf3, S, 0, 0, 0);
      __builtin_amdgcn_s_setprio(0);
    }
    if (diag){
      #pragma unroll
      for (int r = 0; r < 16; ++r){
        int kk = (r & 3) + 8*(r >> 2) + 4*hl;
        if (kk > lq) S[r] = -3.0e38f;
      }
    }
    float a0 = fmaxf(fmaxf(S[0],S[1]),  fmaxf(S[2],S[3]));
    float a1 = fmaxf(fmaxf(S[4],S[5]),  fmaxf(S[6],S[7]));
    float a2 = fmaxf(fmaxf(S[8],S[9]),  fmaxf(S[10],S[11]));
    float a3 = fmaxf(fmaxf(S[12],S[13]),fmaxf(S[14],S[15]));
    float pm = fmaxf(fmaxf(a0,a1), fmaxf(a2,a3));
    pm = fmaxf(pm, __shfl_xor(pm, 32));
    if (__any(pm > m + 8.f)){                 // defer-max (T13)
      float mn = fmaxf(m, pm);
      float cr = __builtin_amdgcn_exp2f(m - mn);
      l *= cr;
      #pragma unroll
      for (int r = 0; r < 16; ++r){ acc0[r] *= cr; acc1[r] *= cr; }
      m = mn;
    }
    #pragma unroll
    for (int r = 0; r < 16; ++r) S[r] = __builtin_amdgcn_exp2f(S[r] - m);
    l += ((S[0]+S[1])+(S[2]+S[3])) + ((S[4]+S[5])+(S[6]+S[7]))
       + ((S[8]+S[9])+(S[10]+S[11])) + ((S[12]+S[13])+(S[14]+S[15]));
    u32 g0a = cvtpk(S[0], S[1]),  g0b = cvtpk(S[2], S[3]);
    u32 g1a = cvtpk(S[4], S[5]),  g1b = cvtpk(S[6], S[7]);
    u32 g2a = cvtpk(S[8], S[9]),  g2b = cvtpk(S[10],S[11]);
    u32 g3a = cvtpk(S[12],S[13]), g3b = cvtpk(S[14],S[15]);
    u32 s0a = hl ? g0a : g1a, s0b = hl ? g0b : g1b;
    u32 e0a = (u32)__shfl_xor((int)s0a, 32), e0b = (u32)__shfl_xor((int)s0b, 32);
    u32 m0a = hl ? g1a : g0a, m0b = hl ? g1b : g0b;
    u32 s1a = hl ? g2a : g3a, s1b = hl ? g2b : g3b;
    u32 e1a = (u32)__shfl_xor((int)s1a, 32), e1b = (u32)__shfl_xor((int)s1b, 32);
    u32 m1a = hl ? g3a : g2a, m1b = hl ? g3b : g2b;
    u32x4 A0 = { hl ? e0a : m0a, hl ? e0b : m0b, hl ? m0a : e0a, hl ? m0b : e0b };
    u32x4 A1 = { hl ? e1a : m1a, hl ? e1b : m1b, hl ? m1a : e1a, hl ? m1b : e1b };
    bf16x8 pa0 = __builtin_bit_cast(bf16x8, A0);
    bf16x8 pa1 = __builtin_bit_cast(bf16x8, A1);
    bf16x8 vf00 = *(const bf16x8*)(vb + lq*32 + hl*16);
    bf16x8 vf01 = *(const bf16x8*)(vb + lq*32 + hl*16 + 1024);
    bf16x8 vf10 = *(const bf16x8*)(vb + lq*32 + hl*16 + 2048);
    bf16x8 vf11 = *(const bf16x8*)(vb + lq*32 + hl*16 + 3072);
    __builtin_amdgcn_s_setprio(1);
    acc0 = __builtin_amdgcn_mfma_f32_32x32x16_bf16(vf00, pa0, acc0, 0, 0, 0);
    acc0 = __builtin_amdgcn_mfma_f32_32x32x16_bf16(vf10, pa1, acc0, 0, 0, 0);
    acc1 = __builtin_amdgcn_mfma_f32_32x32x16_bf16(vf01, pa0, acc1, 0, 0, 0);
    acc1 = __builtin_amdgcn_mfma_f32_32x32x16_bf16(vf11, pa1, acc1, 0, 0, 0);
    __builtin_amdgcn_s_setprio(0);
  };

  STAGE(0, 0);
  __syncthreads();
  int p = 0;
  for (int j0 = 0; j0 <= qmax0; j0 += 64){
    if (j0 + 64 <= qmax0) STAGE(p^1, j0 + 64);
    if (j0 <= q0){
      const char* kb = (const char*)&kv[p][0];
      GROUP(kb, kb + 8192, j0 == q0);
      if (j0 + 32 <= q0)
        GROUP(kb + 4096, kb + 12288, j0 + 32 == q0);
    }
    __syncthreads();                          // drains vmcnt (stages landed) + frees buf[p]
    p ^= 1;
  }
  // epilogue: merge lane-pair denominators, normalize, transpose via LDS, store
  l += __shfl_xor(l, 32);
  float inv = __builtin_amdgcn_rcpf(l);
  char* tbc = (char*)kv + w*4096;
  #pragma unroll
  for (int r = 0; r < 16; ++r){
    int d0 = (r & 3) + 8*(r >> 2) + 4*hl;
    *(u16*)(tbc + lq*128 + ((2*d0)      ^ ((lq & 7) << 4))) = f2bf(acc0[r] * inv);
    *(u16*)(tbc + lq*128 + ((2*(d0+32)) ^ ((lq & 7) << 4))) = f2bf(acc1[r] * inv);
  }
  int qr2 = lane >> 1, chb = (lane & 1) * 4;
  u16* cp = ctx + (size_t)(b*SEQ + q0 + qr2)*D_MODEL + h*HEAD_DIM;
  #pragma unroll
  for (int i = 0; i < 4; ++i){
    int ch = chb + i;
    u16x8 vv = *(const u16x8*)(tbc + qr2*128 + 16*(ch ^ (qr2 & 7)));
    *(u16x8*)&cp[ch*8] = vv;
  }
}

extern "C" void kernel_launch(void* const* d_in, const int* in_sizes, int n_in,
                              void* d_out, int out_size, void* d_ws, size_t ws_size,
                              hipStream_t stream){
  const float* x  = (const float*)d_in[0];
  const int*  pos = (const int*)d_in[1];
  const float* Wq = (const float*)d_in[2];
  const float* Wk = (const float*)d_in[3];
  const float* Wv = (const float*)d_in[4];
  const float* Wo = (const float*)d_in[5];
  float* out = (float*)d_out;
  char* ws = (char*)d_ws;
  u16* xb   = (u16*)(ws);                    // 16 MB  x bf16 (reused as ctx later)
  u16* wt   = (u16*)(ws + 16777216);         // 8 MB   Wt q,k,v,o transposed bf16 (q/k perm'd)
  u16* qb   = (u16*)(ws + 25165824);         // 16 MB  q row-major (roped, scaled, perm'd)
  u16* kbh  = (u16*)(ws + 41943040);         // 16 MB  k [b][h][s][64] (roped, perm'd)
  u16* vt2  = (u16*)(ws + 58720256);         // 16 MB  v [b][h][s/16][d][16]
  float2* tab = (float2*)(ws + 75497472);    // 512 KB rope table
  u16* ctxb = xb;

  k_prep<<<12544, 256, 0, stream>>>(x, Wq, Wk, Wv, Wo, pos, xb, wt, tab);
  k_gqkv<<<dim3(64,12), 512, 0, stream>>>(xb, wt, tab, qb, kbh, vt2);
  k_attn<<<dim3(1024), 256, 0, stream>>>(qb, kbh, vt2, ctxb);
  k_gwo<<<dim3(64,8), 256, 0, stream>>>(ctxb, wt + 3145728, out);
}

// Round 15
// 175.933 us; speedup vs baseline: 1.0139x; 1.0139x over previous
//
#include <hip/hip_runtime.h>

typedef unsigned short u16;
typedef unsigned int   u32;
typedef __bf16  bf16x8 __attribute__((ext_vector_type(8)));
typedef float   f32x4  __attribute__((ext_vector_type(4)));
typedef float   f32x16 __attribute__((ext_vector_type(16)));
typedef u16     u16x4  __attribute__((ext_vector_type(4)));
typedef u16     u16x8  __attribute__((ext_vector_type(8)));
typedef u32     u32x4  __attribute__((ext_vector_type(4)));

#define D_MODEL 1024
#define N_HEADS 16
#define HEAD_DIM 64
#define BATCH 4
#define SEQ 2048
#define MROWS (BATCH*SEQ)

__device__ __forceinline__ u16 f2bf(float f){
  unsigned u = __builtin_bit_cast(unsigned, f);
  u += 0x7fffu + ((u >> 16) & 1u);
  return (u16)(u >> 16);
}
__device__ __forceinline__ float bf2f(u16 h){
  unsigned u = ((unsigned)h) << 16;
  return __builtin_bit_cast(float, u);
}
__device__ __forceinline__ u32 cvtpk(float a, float b){
  u32 r; asm("v_cvt_pk_bf16_f32 %0, %1, %2" : "=v"(r) : "v"(a), "v"(b)); return r;
}
__device__ __forceinline__ void gload_lds16(const u16* g, u16* l){
  __builtin_amdgcn_global_load_lds((const __attribute__((address_space(1))) void*)g,
                                   (__attribute__((address_space(3))) void*)l, 16, 0, 0);
}
#define MFMA16(a,b,c) __builtin_amdgcn_mfma_f32_16x16x32_bf16((a),(b),(c),0,0,0)

// ---------- fused prep: x->bf16 | W transpose (+q/k head-perm) | RoPE table ----------
__global__ void k_prep(const float* __restrict__ x, const float* __restrict__ Wq,
                       const float* __restrict__ Wk, const float* __restrict__ Wv,
                       const float* __restrict__ Wo, const int* __restrict__ pos,
                       u16* __restrict__ xb, u16* __restrict__ wt, float2* __restrict__ tab){
  __shared__ float t[32][33];
  const int blk = blockIdx.x, tid = threadIdx.x;
  if (blk < 8192){                              // ---- x fp32 -> bf16 (float4/thread)
    int i = blk * 256 + tid;
    float4 v = reinterpret_cast<const float4*>(x)[i];
    u16x4 o;
    o.x = f2bf(v.x); o.y = f2bf(v.y); o.z = f2bf(v.z); o.w = f2bf(v.w);
    *reinterpret_cast<u16x4*>(xb + (size_t)i * 4) = o;
  } else if (blk < 12288){                      // ---- W [k][n] -> Wt [n][k] bf16
    int idx = blk - 8192;
    int z = idx >> 10;
    int n0 = (idx & 31) * 32, k0 = ((idx >> 5) & 31) * 32;
    const float* W = (z==0)?Wq:(z==1)?Wk:(z==2)?Wv:Wo;
    u16* O = wt + (size_t)z * (D_MODEL*(size_t)D_MODEL);
    int tx = tid & 31, ty = tid >> 5;
    #pragma unroll
    for (int i = ty; i < 32; i += 8) t[i][tx] = W[(size_t)(k0+i)*D_MODEL + n0 + tx];
    __syncthreads();
    #pragma unroll
    for (int i = ty; i < 32; i += 8){
      int n = n0 + i;
      int np = n;
      if (z < 2){ int d = n & 63; np = (n & ~63) | ((d & 1) << 5) | (d >> 1); }
      O[(size_t)np*D_MODEL + k0 + tx] = f2bf(t[tx][i]);
    }
  } else {                                      // ---- RoPE cos/sin table
    int i = (blk - 12288) * 256 + tid;          // SEQ*32 entries
    int s = i >> 5, f = i & 31;
    float inv = exp2f(-(float)f * (13.287712379549449f / 32.0f));
    float a = (float)pos[s] * inv;
    float sn, cs;
    sincosf(a, &sn, &cs);
    tab[i] = make_float2(cs, sn);
  }
}

// ---------- QKV GEMM: 128x256 tile, BK=32, 8 waves, 3-buffer counted-vmcnt,
// ---------- T2-swizzled LDS, fine phase interleave + setprio (r13 exact) ----------
__global__ __launch_bounds__(512, 4) void k_gqkv(const u16* __restrict__ A, const u16* __restrict__ Bt,
                                                 const float2* __restrict__ tab,
                                                 u16* __restrict__ qout, u16* __restrict__ kout,
                                                 u16* __restrict__ vout){
  __shared__ u16 sh[3*12288];   // 72 KB: per buf: A 128x32 @0 (4096 u16), B 256x32 @4096 (8192 u16)
  const int tid = threadIdx.x, lane = tid & 63, w = tid >> 6;
  const int lr = lane & 15, lg = lane >> 4;
  const int m0 = blockIdx.x * 128, n0 = blockIdx.y * 256;   // m fast (r9 order)
  const int wm = w >> 2, wn = w & 3;
  const int ra = tid >> 2;
  const int sca = ((tid & 3) ^ ((ra >> 1) & 3)) << 3;
  const u16* gA  = A  + (size_t)(m0 + ra)*1024 + sca;
  const u16* gB0 = Bt + (size_t)(n0 + ra)*1024 + sca;
  const int rb1 = 128 + ra;
  const u16* gB1 = Bt + (size_t)(n0 + rb1)*1024 + (((tid & 3) ^ ((rb1 >> 1) & 3)) << 3);
  const int dA  = w*512;
  const int dB0 = 4096 + w*512;
  const int dB1 = 8192 + w*512;
  int aoff[4], boff[4];
  #pragma unroll
  for (int mi = 0; mi < 4; ++mi){ int r_ = wm*64 + mi*16 + lr; aoff[mi] = r_*32 + ((lg ^ ((r_>>1)&3)) << 3); }
  #pragma unroll
  for (int ni = 0; ni < 4; ++ni){ int r_ = wn*64 + ni*16 + lr; boff[ni] = 4096 + r_*32 + ((lg ^ ((r_>>1)&3)) << 3); }

  f32x4 acc[4][4] = {};
#define SA_(base, t)  gload_lds16(gA  + (size_t)(t)*32, sh + (base) + dA)
#define SB0_(base, t) gload_lds16(gB0 + (size_t)(t)*32, sh + (base) + dB0)
#define SB1_(base, t) gload_lds16(gB1 + (size_t)(t)*32, sh + (base) + dB1)
  SA_(0,0); SB0_(0,0); SB1_(0,0);
  SA_(12288,1); SB0_(12288,1); SB1_(12288,1);
  int b0 = 0, b1 = 12288, b2 = 24576;
  #pragma unroll 1
  for (int t = 0; t < 32; ++t){
    if (t < 31) { asm volatile("s_waitcnt vmcnt(3) lgkmcnt(0)" ::: "memory"); }
    else        { asm volatile("s_waitcnt vmcnt(0) lgkmcnt(0)" ::: "memory"); }
    __builtin_amdgcn_s_barrier();
    __builtin_amdgcn_sched_barrier(0);
    const u16* Sb = sh + b0;
    bf16x8 af0 = *(const bf16x8*)&Sb[aoff[0]];
    bf16x8 af1 = *(const bf16x8*)&Sb[aoff[1]];
    bf16x8 af2 = *(const bf16x8*)&Sb[aoff[2]];
    bf16x8 af3 = *(const bf16x8*)&Sb[aoff[3]];
    bf16x8 vb0 = *(const bf16x8*)&Sb[boff[0]];
    bf16x8 vb1 = *(const bf16x8*)&Sb[boff[1]];
    if (t < 30){ SA_(b2, t+2); }
    __builtin_amdgcn_s_setprio(1);
    acc[0][0] = MFMA16(af0, vb0, acc[0][0]);
    acc[1][0] = MFMA16(af1, vb0, acc[1][0]);
    acc[2][0] = MFMA16(af2, vb0, acc[2][0]);
    acc[3][0] = MFMA16(af3, vb0, acc[3][0]);
    acc[0][1] = MFMA16(af0, vb1, acc[0][1]);
    acc[1][1] = MFMA16(af1, vb1, acc[1][1]);
    acc[2][1] = MFMA16(af2, vb1, acc[2][1]);
    acc[3][1] = MFMA16(af3, vb1, acc[3][1]);
    __builtin_amdgcn_s_setprio(0);
    bf16x8 vb2 = *(const bf16x8*)&Sb[boff[2]];
    bf16x8 vb3 = *(const bf16x8*)&Sb[boff[3]];
    if (t < 30){ SB0_(b2, t+2); SB1_(b2, t+2); }
    __builtin_amdgcn_s_setprio(1);
    acc[0][2] = MFMA16(af0, vb2, acc[0][2]);
    acc[1][2] = MFMA16(af1, vb2, acc[1][2]);
    acc[2][2] = MFMA16(af2, vb2, acc[2][2]);
    acc[3][2] = MFMA16(af3, vb2, acc[3][2]);
    acc[0][3] = MFMA16(af0, vb3, acc[0][3]);
    acc[1][3] = MFMA16(af1, vb3, acc[1][3]);
    acc[2][3] = MFMA16(af2, vb3, acc[2][3]);
    acc[3][3] = MFMA16(af3, vb3, acc[3][3]);
    __builtin_amdgcn_s_setprio(0);
    int tmp = b0; b0 = b1; b1 = b2; b2 = tmp;
  }
#undef SA_
#undef SB0_
#undef SB1_

  const int which = n0 >> 10;                 // 0=q 1=k 2=v
  #pragma unroll
  for (int mi = 0; mi < 4; mi++){
    int row = m0 + wm*64 + mi*16 + lg*4;
    #pragma unroll
    for (int ni = 0; ni < 4; ni++){
      int col = n0 + wn*64 + ni*16 + lr;
      int cm = col & 1023;
      int hh = cm >> 6, d = cm & 63;
      f32x4 vv = acc[mi][ni];
      f32x4 vp = acc[mi][ni ^ 2];             // rope partner (in-lane, permuted layout)
      #pragma unroll
      for (int r = 0; r < 4; r++){
        int rr = row + r;
        int bb = rr >> 11, s = rr & (SEQ-1);
        float val = vv[r];
        if (which < 2){
          float e = (ni < 2) ? val : vp[r];
          float o = (ni < 2) ? vp[r] : val;
          float2 cs = tab[s*32 + ((ni & 1) << 4) + lr];
          float ov = (ni < 2) ? (e*cs.x - o*cs.y) : (e*cs.y + o*cs.x);
          if (which == 0){
            ov *= 0.18033688011112042f;       // 0.125 * log2(e)
            qout[(size_t)rr*1024 + cm] = f2bf(ov);
          } else {
            kout[(((size_t)(bb*N_HEADS + hh))*SEQ + s)*64 + d] = f2bf(ov);
          }
        } else {
          vout[(((size_t)(bb*N_HEADS + hh))*(SEQ/16) + (s >> 4))*1024 + d*16 + (s & 15)] = f2bf(val);
        }
      }
    }
  }
}

// ---------- Wo GEMM: 128x128, BK=32, 4 waves, 3-buffer counted-vmcnt
// ---------- + T2 swizzle + fine interleave + setprio (r13 exact) ----------
__global__ __launch_bounds__(256, 4) void k_gwo(const u16* __restrict__ A, const u16* __restrict__ Bt,
                                                float* __restrict__ fout){
  __shared__ u16 sh[3*8192];                 // 48 KB: per buf A 128x32 @0, B 128x32 @4096
  const int tid = threadIdx.x, lane = tid & 63, w = tid >> 6;
  const int lr = lane & 15, lg = lane >> 4;
  const int m0 = blockIdx.x * 128, n0 = blockIdx.y * 128;   // m fast (r9 order)
  const int wm = w >> 1, wn = w & 1;
  const int ra = w*16 + (lane >> 2);
  const int sc = ((lane & 3) ^ ((ra >> 1) & 3)) << 3;
  const u16* gA0 = A  + (size_t)(m0 + ra)*1024 + sc;
  const u16* gA1 = A  + (size_t)(m0 + 64 + ra)*1024 + sc;
  const u16* gB0 = Bt + (size_t)(n0 + ra)*1024 + sc;
  const u16* gB1 = Bt + (size_t)(n0 + 64 + ra)*1024 + sc;
  int aoff[4], boff[4];
  #pragma unroll
  for (int mi = 0; mi < 4; ++mi){ int r_ = wm*64 + mi*16 + lr; aoff[mi] = r_*32 + ((lg ^ ((r_>>1)&3)) << 3); }
  #pragma unroll
  for (int ni = 0; ni < 4; ++ni){ int r_ = wn*64 + ni*16 + lr; boff[ni] = 4096 + r_*32 + ((lg ^ ((r_>>1)&3)) << 3); }
  f32x4 acc[4][4] = {};
#define SAW(base, t) { gload_lds16(gA0 + (size_t)(t)*32, sh + (base) + w*512); \
                       gload_lds16(gA1 + (size_t)(t)*32, sh + (base) + 2048 + w*512); }
#define SBW(base, t) { gload_lds16(gB0 + (size_t)(t)*32, sh + (base) + 4096 + w*512); \
                       gload_lds16(gB1 + (size_t)(t)*32, sh + (base) + 6144 + w*512); }
  SAW(0,0) SBW(0,0)
  SAW(8192,1) SBW(8192,1)
  int b0 = 0, b1 = 8192, b2 = 16384;
  #pragma unroll 1
  for (int t = 0; t < 32; ++t){
    if (t < 31) { asm volatile("s_waitcnt vmcnt(4) lgkmcnt(0)" ::: "memory"); }
    else        { asm volatile("s_waitcnt vmcnt(0) lgkmcnt(0)" ::: "memory"); }
    __builtin_amdgcn_s_barrier();
    __builtin_amdgcn_sched_barrier(0);
    const u16* Sb = sh + b0;
    bf16x8 af0 = *(const bf16x8*)&Sb[aoff[0]];
    bf16x8 af1 = *(const bf16x8*)&Sb[aoff[1]];
    bf16x8 af2 = *(const bf16x8*)&Sb[aoff[2]];
    bf16x8 af3 = *(const bf16x8*)&Sb[aoff[3]];
    bf16x8 vb0 = *(const bf16x8*)&Sb[boff[0]];
    bf16x8 vb1 = *(const bf16x8*)&Sb[boff[1]];
    if (t < 30){ SAW(b2, t+2) }
    __builtin_amdgcn_s_setprio(1);
    acc[0][0] = MFMA16(af0, vb0, acc[0][0]);
    acc[1][0] = MFMA16(af1, vb0, acc[1][0]);
    acc[2][0] = MFMA16(af2, vb0, acc[2][0]);
    acc[3][0] = MFMA16(af3, vb0, acc[3][0]);
    acc[0][1] = MFMA16(af0, vb1, acc[0][1]);
    acc[1][1] = MFMA16(af1, vb1, acc[1][1]);
    acc[2][1] = MFMA16(af2, vb1, acc[2][1]);
    acc[3][1] = MFMA16(af3, vb1, acc[3][1]);
    __builtin_amdgcn_s_setprio(0);
    bf16x8 vb2 = *(const bf16x8*)&Sb[boff[2]];
    bf16x8 vb3 = *(const bf16x8*)&Sb[boff[3]];
    if (t < 30){ SBW(b2, t+2) }
    __builtin_amdgcn_s_setprio(1);
    acc[0][2] = MFMA16(af0, vb2, acc[0][2]);
    acc[1][2] = MFMA16(af1, vb2, acc[1][2]);
    acc[2][2] = MFMA16(af2, vb2, acc[2][2]);
    acc[3][2] = MFMA16(af3, vb2, acc[3][2]);
    acc[0][3] = MFMA16(af0, vb3, acc[0][3]);
    acc[1][3] = MFMA16(af1, vb3, acc[1][3]);
    acc[2][3] = MFMA16(af2, vb3, acc[2][3]);
    acc[3][3] = MFMA16(af3, vb3, acc[3][3]);
    __builtin_amdgcn_s_setprio(0);
    int tmp = b0; b0 = b1; b1 = b2; b2 = tmp;
  }
#undef SAW
#undef SBW
  #pragma unroll
  for (int mi = 0; mi < 4; mi++){
    int row = m0 + wm*64 + mi*16 + lg*4;
    #pragma unroll
    for (int ni = 0; ni < 4; ni++){
      int col = n0 + wn*64 + ni*16 + lr;
      f32x4 vv = acc[mi][ni];
      #pragma unroll
      for (int r = 0; r < 4; r++)
        fout[(size_t)(row + r)*1024 + col] = vv[r];
    }
  }
}

// ---------- causal flash attention: 4-wave blocks, KVBLK=64, K/V shared LDS dbuf ----------
// (r13 exact — best measured)
__global__ __launch_bounds__(256, 3) void k_attn(const u16* __restrict__ q, const u16* __restrict__ k2,
                                                 const u16* __restrict__ v2, u16* __restrict__ ctx){
  __shared__ u16 kv[2][8192];                 // per buf: K 8KB | V 8KB
  const int lane = threadIdx.x & 63, w = threadIdx.x >> 6;
  const int lq = lane & 31, hl = lane >> 5;
  const int B = blockIdx.x;
  const int bh = B & 63, g = 15 - (B >> 6);
  const int b = bh >> 4, h = bh & 15;
  const int qi = 4*g + w;
  const int q0 = qi * 32;
  const int qmax0 = (4*g + 3) * 32;           // block-uniform loop bound
  const u16* kglob = k2 + (size_t)bh*SEQ*64;
  const u16* vglob = v2 + (size_t)bh*(SEQ/16)*1024;

  const u16* qr_ = q + (size_t)(b*SEQ + q0 + lq)*D_MODEL + h*HEAD_DIM + hl*8;
  bf16x8 qf0 = *(const bf16x8*)&qr_[0];
  bf16x8 qf1 = *(const bf16x8*)&qr_[16];
  bf16x8 qf2 = *(const bf16x8*)&qr_[32];
  bf16x8 qf3 = *(const bf16x8*)&qr_[48];
  f32x16 acc0 = {}, acc1 = {};
  float m = -3.0e38f, l = 0.f;

  const int kr_ = (w<<3) + (lane>>3);                 // stage K row in 0..31
  const int kc_ = ((lane&7) ^ (lane>>3)) << 3;        // swizzled source chunk
  auto STAGE = [&](int bf, int jt){
    gload_lds16(kglob + (size_t)(jt      + kr_)*64 + kc_, &kv[bf][w<<9]);
    gload_lds16(kglob + (size_t)(jt + 32 + kr_)*64 + kc_, &kv[bf][2048 + (w<<9)]);
    gload_lds16(vglob + ((size_t)(jt>>4)<<10)        + (w<<9) + (lane<<3), &kv[bf][4096 + (w<<9)]);
    gload_lds16(vglob + ((size_t)((jt+32)>>4)<<10)   + (w<<9) + (lane<<3), &kv[bf][6144 + (w<<9)]);
  };

  STAGE(0, 0);
  __syncthreads();
  int p = 0;
  for (int j0 = 0; j0 <= qmax0; j0 += 64){
    if (j0 + 64 <= qmax0) STAGE(p^1, j0 + 64);
    if (j0 <= q0){
      const bool g2 = (j0 + 32 <= q0);
      const char* kb = (const char*)&kv[p][0];
      f32x16 S1 = {};
      {
        bf16x8 kf0 = *(const bf16x8*)(kb + lq*128 + (((0+hl) ^ (lq&7))<<4));
        bf16x8 kf1 = *(const bf16x8*)(kb + lq*128 + (((2+hl) ^ (lq&7))<<4));
        bf16x8 kf2 = *(const bf16x8*)(kb + lq*128 + (((4+hl) ^ (lq&7))<<4));
        bf16x8 kf3 = *(const bf16x8*)(kb + lq*128 + (((6+hl) ^ (lq&7))<<4));
        S1 = __builtin_amdgcn_mfma_f32_32x32x16_bf16(kf0, qf0, S1, 0, 0, 0);
        S1 = __builtin_amdgcn_mfma_f32_32x32x16_bf16(kf1, qf1, S1, 0, 0, 0);
        S1 = __builtin_amdgcn_mfma_f32_32x32x16_bf16(kf2, qf2, S1, 0, 0, 0);
        S1 = __builtin_amdgcn_mfma_f32_32x32x16_bf16(kf3, qf3, S1, 0, 0, 0);
      }
      if (j0 == q0){
        #pragma unroll
        for (int r = 0; r < 16; ++r){
          int kk = (r & 3) + 8*(r >> 2) + 4*hl;
          if (kk > lq) S1[r] = -3.0e38f;
        }
      }
      f32x16 S2 = {};
      if (g2){
        const char* kb2 = kb + 4096;
        bf16x8 kf0 = *(const bf16x8*)(kb2 + lq*128 + (((0+hl) ^ (lq&7))<<4));
        bf16x8 kf1 = *(const bf16x8*)(kb2 + lq*128 + (((2+hl) ^ (lq&7))<<4));
        bf16x8 kf2 = *(const bf16x8*)(kb2 + lq*128 + (((4+hl) ^ (lq&7))<<4));
        bf16x8 kf3 = *(const bf16x8*)(kb2 + lq*128 + (((6+hl) ^ (lq&7))<<4));
        S2 = __builtin_amdgcn_mfma_f32_32x32x16_bf16(kf0, qf0, S2, 0, 0, 0);
        S2 = __builtin_amdgcn_mfma_f32_32x32x16_bf16(kf1, qf1, S2, 0, 0, 0);
        S2 = __builtin_amdgcn_mfma_f32_32x32x16_bf16(kf2, qf2, S2, 0, 0, 0);
        S2 = __builtin_amdgcn_mfma_f32_32x32x16_bf16(kf3, qf3, S2, 0, 0, 0);
        if (j0 + 32 == q0){
          #pragma unroll
          for (int r = 0; r < 16; ++r){
            int kk = (r & 3) + 8*(r >> 2) + 4*hl;
            if (kk > lq) S2[r] = -3.0e38f;
          }
        }
      }
      float pm = fmaxf(fmaxf(fmaxf(S1[0],S1[1]), fmaxf(S1[2],S1[3])),
                       fmaxf(fmaxf(S1[4],S1[5]), fmaxf(S1[6],S1[7])));
      pm = fmaxf(pm, fmaxf(fmaxf(fmaxf(S1[8],S1[9]), fmaxf(S1[10],S1[11])),
                           fmaxf(fmaxf(S1[12],S1[13]),fmaxf(S1[14],S1[15]))));
      if (g2){
        float pm2 = fmaxf(fmaxf(fmaxf(S2[0],S2[1]), fmaxf(S2[2],S2[3])),
                          fmaxf(fmaxf(S2[4],S2[5]), fmaxf(S2[6],S2[7])));
        pm2 = fmaxf(pm2, fmaxf(fmaxf(fmaxf(S2[8],S2[9]), fmaxf(S2[10],S2[11])),
                               fmaxf(fmaxf(S2[12],S2[13]),fmaxf(S2[14],S2[15]))));
        pm = fmaxf(pm, pm2);
      }
      pm = fmaxf(pm, __shfl_xor(pm, 32));
      if (__any(pm > m + 8.f)){               // defer-max (T13)
        float mn = fmaxf(m, pm);
        float cr = __builtin_amdgcn_exp2f(m - mn);
        l *= cr;
        #pragma unroll
        for (int r = 0; r < 16; ++r){ acc0[r] *= cr; acc1[r] *= cr; }
        m = mn;
      }
      #pragma unroll
      for (int r = 0; r < 16; ++r) S1[r] = __builtin_amdgcn_exp2f(S1[r] - m);
      l += ((S1[0]+S1[1])+(S1[2]+S1[3])) + ((S1[4]+S1[5])+(S1[6]+S1[7]))
         + ((S1[8]+S1[9])+(S1[10]+S1[11])) + ((S1[12]+S1[13])+(S1[14]+S1[15]));
      {
        u32 g0a = cvtpk(S1[0], S1[1]),  g0b = cvtpk(S1[2], S1[3]);
        u32 g1a = cvtpk(S1[4], S1[5]),  g1b = cvtpk(S1[6], S1[7]);
        u32 g2a = cvtpk(S1[8], S1[9]),  g2b = cvtpk(S1[10],S1[11]);
        u32 g3a = cvtpk(S1[12],S1[13]), g3b = cvtpk(S1[14],S1[15]);
        u32 s0a = hl ? g0a : g1a, s0b = hl ? g0b : g1b;
        u32 e0a = (u32)__shfl_xor((int)s0a, 32), e0b = (u32)__shfl_xor((int)s0b, 32);
        u32 m0a = hl ? g1a : g0a, m0b = hl ? g1b : g0b;
        u32 s1a = hl ? g2a : g3a, s1b = hl ? g2b : g3b;
        u32 e1a = (u32)__shfl_xor((int)s1a, 32), e1b = (u32)__shfl_xor((int)s1b, 32);
        u32 m1a = hl ? g3a : g2a, m1b = hl ? g3b : g2b;
        u32x4 A0 = { hl ? e0a : m0a, hl ? e0b : m0b, hl ? m0a : e0a, hl ? m0b : e0b };
        u32x4 A1 = { hl ? e1a : m1a, hl ? e1b : m1b, hl ? m1a : e1a, hl ? m1b : e1b };
        bf16x8 pa0 = __builtin_bit_cast(bf16x8, A0);
        bf16x8 pa1 = __builtin_bit_cast(bf16x8, A1);
        const char* vb = kb + 8192;
        bf16x8 vf00 = *(const bf16x8*)(vb + lq*32 + hl*16);
        bf16x8 vf01 = *(const bf16x8*)(vb + lq*32 + hl*16 + 1024);
        bf16x8 vf10 = *(const bf16x8*)(vb + lq*32 + hl*16 + 2048);
        bf16x8 vf11 = *(const bf16x8*)(vb + lq*32 + hl*16 + 3072);
        acc0 = __builtin_amdgcn_mfma_f32_32x32x16_bf16(vf00, pa0, acc0, 0, 0, 0);
        acc0 = __builtin_amdgcn_mfma_f32_32x32x16_bf16(vf10, pa1, acc0, 0, 0, 0);
        acc1 = __builtin_amdgcn_mfma_f32_32x32x16_bf16(vf01, pa0, acc1, 0, 0, 0);
        acc1 = __builtin_amdgcn_mfma_f32_32x32x16_bf16(vf11, pa1, acc1, 0, 0, 0);
      }
      if (g2){
        #pragma unroll
        for (int r = 0; r < 16; ++r) S2[r] = __builtin_amdgcn_exp2f(S2[r] - m);
        l += ((S2[0]+S2[1])+(S2[2]+S2[3])) + ((S2[4]+S2[5])+(S2[6]+S2[7]))
           + ((S2[8]+S2[9])+(S2[10]+S2[11])) + ((S2[12]+S2[13])+(S2[14]+S2[15]));
        u32 g0a = cvtpk(S2[0], S2[1]),  g0b = cvtpk(S2[2], S2[3]);
        u32 g1a = cvtpk(S2[4], S2[5]),  g1b = cvtpk(S2[6], S2[7]);
        u32 g2a_ = cvtpk(S2[8], S2[9]), g2b_ = cvtpk(S2[10],S2[11]);
        u32 g3a = cvtpk(S2[12],S2[13]), g3b = cvtpk(S2[14],S2[15]);
        u32 s0a = hl ? g0a : g1a, s0b = hl ? g0b : g1b;
        u32 e0a = (u32)__shfl_xor((int)s0a, 32), e0b = (u32)__shfl_xor((int)s0b, 32);
        u32 m0a = hl ? g1a : g0a, m0b = hl ? g1b : g0b;
        u32 s1a = hl ? g2a_ : g3a, s1b = hl ? g2b_ : g3b;
        u32 e1a = (u32)__shfl_xor((int)s1a, 32), e1b = (u32)__shfl_xor((int)s1b, 32);
        u32 m1a = hl ? g3a : g2a_, m1b = hl ? g3b : g2b_;
        u32x4 A0 = { hl ? e0a : m0a, hl ? e0b : m0b, hl ? m0a : e0a, hl ? m0b : e0b };
        u32x4 A1 = { hl ? e1a : m1a, hl ? e1b : m1b, hl ? m1a : e1a, hl ? m1b : e1b };
        bf16x8 pa0 = __builtin_bit_cast(bf16x8, A0);
        bf16x8 pa1 = __builtin_bit_cast(bf16x8, A1);
        const char* vb = kb + 12288;
        bf16x8 vf00 = *(const bf16x8*)(vb + lq*32 + hl*16);
        bf16x8 vf01 = *(const bf16x8*)(vb + lq*32 + hl*16 + 1024);
        bf16x8 vf10 = *(const bf16x8*)(vb + lq*32 + hl*16 + 2048);
        bf16x8 vf11 = *(const bf16x8*)(vb + lq*32 + hl*16 + 3072);
        acc0 = __builtin_amdgcn_mfma_f32_32x32x16_bf16(vf00, pa0, acc0, 0, 0, 0);
        acc0 = __builtin_amdgcn_mfma_f32_32x32x16_bf16(vf10, pa1, acc0, 0, 0, 0);
        acc1 = __builtin_amdgcn_mfma_f32_32x32x16_bf16(vf01, pa0, acc1, 0, 0, 0);
        acc1 = __builtin_amdgcn_mfma_f32_32x32x16_bf16(vf11, pa1, acc1, 0, 0, 0);
      }
    }
    __syncthreads();
    p ^= 1;
  }
  l += __shfl_xor(l, 32);
  float inv = __builtin_amdgcn_rcpf(l);
  char* tbc = (char*)kv + w*4096;
  #pragma unroll
  for (int r = 0; r < 16; ++r){
    int d0 = (r & 3) + 8*(r >> 2) + 4*hl;
    *(u16*)(tbc + lq*128 + ((2*d0)      ^ ((lq & 7) << 4))) = f2bf(acc0[r] * inv);
    *(u16*)(tbc + lq*128 + ((2*(d0+32)) ^ ((lq & 7) << 4))) = f2bf(acc1[r] * inv);
  }
  int qr2 = lane >> 1, chb = (lane & 1) * 4;
  u16* cp = ctx + (size_t)(b*SEQ + q0 + qr2)*D_MODEL + h*HEAD_DIM;
  #pragma unroll
  for (int i = 0; i < 4; ++i){
    int ch = chb + i;
    u16x8 vv = *(const u16x8*)(tbc + qr2*128 + 16*(ch ^ (qr2 & 7)));
    *(u16x8*)&cp[ch*8] = vv;
  }
}

extern "C" void kernel_launch(void* const* d_in, const int* in_sizes, int n_in,
                              void* d_out, int out_size, void* d_ws, size_t ws_size,
                              hipStream_t stream){
  const float* x  = (const float*)d_in[0];
  const int*  pos = (const int*)d_in[1];
  const float* Wq = (const float*)d_in[2];
  const float* Wk = (const float*)d_in[3];
  const float* Wv = (const float*)d_in[4];
  const float* Wo = (const float*)d_in[5];
  float* out = (float*)d_out;
  char* ws = (char*)d_ws;
  u16* xb   = (u16*)(ws);                    // 16 MB  x bf16 (reused as ctx later)
  u16* wt   = (u16*)(ws + 16777216);         // 8 MB   Wt q,k,v,o transposed bf16 (q/k perm'd)
  u16* qb   = (u16*)(ws + 25165824);         // 16 MB  q row-major (roped, scaled, perm'd)
  u16* kbh  = (u16*)(ws + 41943040);         // 16 MB  k [b][h][s][64] (roped, perm'd)
  u16* vt2  = (u16*)(ws + 58720256);         // 16 MB  v [b][h][s/16][d][16]
  float2* tab = (float2*)(ws + 75497472);    // 512 KB rope table
  u16* ctxb = xb;

  k_prep<<<12544, 256, 0, stream>>>(x, Wq, Wk, Wv, Wo, pos, xb, wt, tab);
  k_gqkv<<<dim3(64,12), 512, 0, stream>>>(xb, wt, tab, qb, kbh, vt2);
  k_attn<<<dim3(1024), 256, 0, stream>>>(qb, kbh, vt2, ctxb);
  k_gwo<<<dim3(64,8), 256, 0, stream>>>(ctxb, wt + 3145728, out);
}

// Round 16
// 174.840 us; speedup vs baseline: 1.0203x; 1.0063x over previous
//
#include <hip/hip_runtime.h>

typedef unsigned short u16;
typedef unsigned int   u32;
typedef __bf16  bf16x8 __attribute__((ext_vector_type(8)));
typedef float   f32x4  __attribute__((ext_vector_type(4)));
typedef float   f32x16 __attribute__((ext_vector_type(16)));
typedef u16     u16x4  __attribute__((ext_vector_type(4)));
typedef u16     u16x8  __attribute__((ext_vector_type(8)));
typedef u32     u32x4  __attribute__((ext_vector_type(4)));

#define D_MODEL 1024
#define N_HEADS 16
#define HEAD_DIM 64
#define BATCH 4
#define SEQ 2048
#define MROWS (BATCH*SEQ)

__device__ __forceinline__ u16 f2bf(float f){
  unsigned u = __builtin_bit_cast(unsigned, f);
  u += 0x7fffu + ((u >> 16) & 1u);
  return (u16)(u >> 16);
}
__device__ __forceinline__ float bf2f(u16 h){
  unsigned u = ((unsigned)h) << 16;
  return __builtin_bit_cast(float, u);
}
__device__ __forceinline__ u32 cvtpk(float a, float b){
  u32 r; asm("v_cvt_pk_bf16_f32 %0, %1, %2" : "=v"(r) : "v"(a), "v"(b)); return r;
}
__device__ __forceinline__ void gload_lds16(const u16* g, u16* l){
  __builtin_amdgcn_global_load_lds((const __attribute__((address_space(1))) void*)g,
                                   (__attribute__((address_space(3))) void*)l, 16, 0, 0);
}
#define MFMA16(a,b,c) __builtin_amdgcn_mfma_f32_16x16x32_bf16((a),(b),(c),0,0,0)

// ---------- fused prep: x->bf16 | W transpose (+q/k head-perm) | RoPE table ----------
__global__ void k_prep(const float* __restrict__ x, const float* __restrict__ Wq,
                       const float* __restrict__ Wk, const float* __restrict__ Wv,
                       const float* __restrict__ Wo, const int* __restrict__ pos,
                       u16* __restrict__ xb, u16* __restrict__ wt, float2* __restrict__ tab){
  __shared__ float t[32][33];
  const int blk = blockIdx.x, tid = threadIdx.x;
  if (blk < 8192){                              // ---- x fp32 -> bf16 (float4/thread)
    int i = blk * 256 + tid;
    float4 v = reinterpret_cast<const float4*>(x)[i];
    u16x4 o;
    o.x = f2bf(v.x); o.y = f2bf(v.y); o.z = f2bf(v.z); o.w = f2bf(v.w);
    *reinterpret_cast<u16x4*>(xb + (size_t)i * 4) = o;
  } else if (blk < 12288){                      // ---- W [k][n] -> Wt [n][k] bf16
    int idx = blk - 8192;
    int z = idx >> 10;
    int n0 = (idx & 31) * 32, k0 = ((idx >> 5) & 31) * 32;
    const float* W = (z==0)?Wq:(z==1)?Wk:(z==2)?Wv:Wo;
    u16* O = wt + (size_t)z * (D_MODEL*(size_t)D_MODEL);
    int tx = tid & 31, ty = tid >> 5;
    #pragma unroll
    for (int i = ty; i < 32; i += 8) t[i][tx] = W[(size_t)(k0+i)*D_MODEL + n0 + tx];
    __syncthreads();
    #pragma unroll
    for (int i = ty; i < 32; i += 8){
      int n = n0 + i;
      int np = n;
      if (z < 2){ int d = n & 63; np = (n & ~63) | ((d & 1) << 5) | (d >> 1); }
      O[(size_t)np*D_MODEL + k0 + tx] = f2bf(t[tx][i]);
    }
  } else {                                      // ---- RoPE cos/sin table
    int i = (blk - 12288) * 256 + tid;          // SEQ*32 entries
    int s = i >> 5, f = i & 31;
    float inv = exp2f(-(float)f * (13.287712379549449f / 32.0f));
    float a = (float)pos[s] * inv;
    float sn, cs;
    sincosf(a, &sn, &cs);
    tab[i] = make_float2(cs, sn);
  }
}

// ---------- QKV GEMM: 128x256 tile, BK=32, 8 waves, 3-buffer counted-vmcnt,
// ---------- T2-swizzled LDS, fine phase interleave + setprio (r13 exact) ----------
__global__ __launch_bounds__(512, 4) void k_gqkv(const u16* __restrict__ A, const u16* __restrict__ Bt,
                                                 const float2* __restrict__ tab,
                                                 u16* __restrict__ qout, u16* __restrict__ kout,
                                                 u16* __restrict__ vout){
  __shared__ u16 sh[3*12288];   // 72 KB: per buf: A 128x32 @0 (4096 u16), B 256x32 @4096 (8192 u16)
  const int tid = threadIdx.x, lane = tid & 63, w = tid >> 6;
  const int lr = lane & 15, lg = lane >> 4;
  const int m0 = blockIdx.x * 128, n0 = blockIdx.y * 256;   // m fast (r9 order)
  const int wm = w >> 2, wn = w & 3;
  const int ra = tid >> 2;
  const int sca = ((tid & 3) ^ ((ra >> 1) & 3)) << 3;
  const u16* gA  = A  + (size_t)(m0 + ra)*1024 + sca;
  const u16* gB0 = Bt + (size_t)(n0 + ra)*1024 + sca;
  const int rb1 = 128 + ra;
  const u16* gB1 = Bt + (size_t)(n0 + rb1)*1024 + (((tid & 3) ^ ((rb1 >> 1) & 3)) << 3);
  const int dA  = w*512;
  const int dB0 = 4096 + w*512;
  const int dB1 = 8192 + w*512;
  int aoff[4], boff[4];
  #pragma unroll
  for (int mi = 0; mi < 4; ++mi){ int r_ = wm*64 + mi*16 + lr; aoff[mi] = r_*32 + ((lg ^ ((r_>>1)&3)) << 3); }
  #pragma unroll
  for (int ni = 0; ni < 4; ++ni){ int r_ = wn*64 + ni*16 + lr; boff[ni] = 4096 + r_*32 + ((lg ^ ((r_>>1)&3)) << 3); }

  f32x4 acc[4][4] = {};
#define SA_(base, t)  gload_lds16(gA  + (size_t)(t)*32, sh + (base) + dA)
#define SB0_(base, t) gload_lds16(gB0 + (size_t)(t)*32, sh + (base) + dB0)
#define SB1_(base, t) gload_lds16(gB1 + (size_t)(t)*32, sh + (base) + dB1)
  SA_(0,0); SB0_(0,0); SB1_(0,0);
  SA_(12288,1); SB0_(12288,1); SB1_(12288,1);
  int b0 = 0, b1 = 12288, b2 = 24576;
  #pragma unroll 1
  for (int t = 0; t < 32; ++t){
    if (t < 31) { asm volatile("s_waitcnt vmcnt(3) lgkmcnt(0)" ::: "memory"); }
    else        { asm volatile("s_waitcnt vmcnt(0) lgkmcnt(0)" ::: "memory"); }
    __builtin_amdgcn_s_barrier();
    __builtin_amdgcn_sched_barrier(0);
    const u16* Sb = sh + b0;
    bf16x8 af0 = *(const bf16x8*)&Sb[aoff[0]];
    bf16x8 af1 = *(const bf16x8*)&Sb[aoff[1]];
    bf16x8 af2 = *(const bf16x8*)&Sb[aoff[2]];
    bf16x8 af3 = *(const bf16x8*)&Sb[aoff[3]];
    bf16x8 vb0 = *(const bf16x8*)&Sb[boff[0]];
    bf16x8 vb1 = *(const bf16x8*)&Sb[boff[1]];
    if (t < 30){ SA_(b2, t+2); }
    __builtin_amdgcn_s_setprio(1);
    acc[0][0] = MFMA16(af0, vb0, acc[0][0]);
    acc[1][0] = MFMA16(af1, vb0, acc[1][0]);
    acc[2][0] = MFMA16(af2, vb0, acc[2][0]);
    acc[3][0] = MFMA16(af3, vb0, acc[3][0]);
    acc[0][1] = MFMA16(af0, vb1, acc[0][1]);
    acc[1][1] = MFMA16(af1, vb1, acc[1][1]);
    acc[2][1] = MFMA16(af2, vb1, acc[2][1]);
    acc[3][1] = MFMA16(af3, vb1, acc[3][1]);
    __builtin_amdgcn_s_setprio(0);
    bf16x8 vb2 = *(const bf16x8*)&Sb[boff[2]];
    bf16x8 vb3 = *(const bf16x8*)&Sb[boff[3]];
    if (t < 30){ SB0_(b2, t+2); SB1_(b2, t+2); }
    __builtin_amdgcn_s_setprio(1);
    acc[0][2] = MFMA16(af0, vb2, acc[0][2]);
    acc[1][2] = MFMA16(af1, vb2, acc[1][2]);
    acc[2][2] = MFMA16(af2, vb2, acc[2][2]);
    acc[3][2] = MFMA16(af3, vb2, acc[3][2]);
    acc[0][3] = MFMA16(af0, vb3, acc[0][3]);
    acc[1][3] = MFMA16(af1, vb3, acc[1][3]);
    acc[2][3] = MFMA16(af2, vb3, acc[2][3]);
    acc[3][3] = MFMA16(af3, vb3, acc[3][3]);
    __builtin_amdgcn_s_setprio(0);
    int tmp = b0; b0 = b1; b1 = b2; b2 = tmp;
  }
#undef SA_
#undef SB0_
#undef SB1_

  const int which = n0 >> 10;                 // 0=q 1=k 2=v
  #pragma unroll
  for (int mi = 0; mi < 4; mi++){
    int row = m0 + wm*64 + mi*16 + lg*4;
    #pragma unroll
    for (int ni = 0; ni < 4; ni++){
      int col = n0 + wn*64 + ni*16 + lr;
      int cm = col & 1023;
      int hh = cm >> 6, d = cm & 63;
      f32x4 vv = acc[mi][ni];
      f32x4 vp = acc[mi][ni ^ 2];             // rope partner (in-lane, permuted layout)
      #pragma unroll
      for (int r = 0; r < 4; r++){
        int rr = row + r;
        int bb = rr >> 11, s = rr & (SEQ-1);
        float val = vv[r];
        if (which < 2){
          float e = (ni < 2) ? val : vp[r];
          float o = (ni < 2) ? vp[r] : val;
          float2 cs = tab[s*32 + ((ni & 1) << 4) + lr];
          float ov = (ni < 2) ? (e*cs.x - o*cs.y) : (e*cs.y + o*cs.x);
          if (which == 0){
            ov *= 0.18033688011112042f;       // 0.125 * log2(e)
            qout[(size_t)rr*1024 + cm] = f2bf(ov);
          } else {
            kout[(((size_t)(bb*N_HEADS + hh))*SEQ + s)*64 + d] = f2bf(ov);
          }
        } else {
          vout[(((size_t)(bb*N_HEADS + hh))*(SEQ/16) + (s >> 4))*1024 + d*16 + (s & 15)] = f2bf(val);
        }
      }
    }
  }
}

// ---------- Wo GEMM: SAME 128x256 8-wave structure as k_gqkv, f32 epilogue.
// ---------- grid (64,4) = 256 blocks = 1 block/CU, single generation, zero tail.
__global__ __launch_bounds__(512, 4) void k_gwo2(const u16* __restrict__ A, const u16* __restrict__ Bt,
                                                 float* __restrict__ fout){
  __shared__ u16 sh[3*12288];   // 72 KB: per buf: A 128x32 @0, B 256x32 @4096
  const int tid = threadIdx.x, lane = tid & 63, w = tid >> 6;
  const int lr = lane & 15, lg = lane >> 4;
  const int m0 = blockIdx.x * 128, n0 = blockIdx.y * 256;
  const int wm = w >> 2, wn = w & 3;
  const int ra = tid >> 2;
  const int sca = ((tid & 3) ^ ((ra >> 1) & 3)) << 3;
  const u16* gA  = A  + (size_t)(m0 + ra)*1024 + sca;
  const u16* gB0 = Bt + (size_t)(n0 + ra)*1024 + sca;
  const int rb1 = 128 + ra;
  const u16* gB1 = Bt + (size_t)(n0 + rb1)*1024 + (((tid & 3) ^ ((rb1 >> 1) & 3)) << 3);
  const int dA  = w*512;
  const int dB0 = 4096 + w*512;
  const int dB1 = 8192 + w*512;
  int aoff[4], boff[4];
  #pragma unroll
  for (int mi = 0; mi < 4; ++mi){ int r_ = wm*64 + mi*16 + lr; aoff[mi] = r_*32 + ((lg ^ ((r_>>1)&3)) << 3); }
  #pragma unroll
  for (int ni = 0; ni < 4; ++ni){ int r_ = wn*64 + ni*16 + lr; boff[ni] = 4096 + r_*32 + ((lg ^ ((r_>>1)&3)) << 3); }

  f32x4 acc[4][4] = {};
#define SA_(base, t)  gload_lds16(gA  + (size_t)(t)*32, sh + (base) + dA)
#define SB0_(base, t) gload_lds16(gB0 + (size_t)(t)*32, sh + (base) + dB0)
#define SB1_(base, t) gload_lds16(gB1 + (size_t)(t)*32, sh + (base) + dB1)
  SA_(0,0); SB0_(0,0); SB1_(0,0);
  SA_(12288,1); SB0_(12288,1); SB1_(12288,1);
  int b0 = 0, b1 = 12288, b2 = 24576;
  #pragma unroll 1
  for (int t = 0; t < 32; ++t){
    if (t < 31) { asm volatile("s_waitcnt vmcnt(3) lgkmcnt(0)" ::: "memory"); }
    else        { asm volatile("s_waitcnt vmcnt(0) lgkmcnt(0)" ::: "memory"); }
    __builtin_amdgcn_s_barrier();
    __builtin_amdgcn_sched_barrier(0);
    const u16* Sb = sh + b0;
    bf16x8 af0 = *(const bf16x8*)&Sb[aoff[0]];
    bf16x8 af1 = *(const bf16x8*)&Sb[aoff[1]];
    bf16x8 af2 = *(const bf16x8*)&Sb[aoff[2]];
    bf16x8 af3 = *(const bf16x8*)&Sb[aoff[3]];
    bf16x8 vb0 = *(const bf16x8*)&Sb[boff[0]];
    bf16x8 vb1 = *(const bf16x8*)&Sb[boff[1]];
    if (t < 30){ SA_(b2, t+2); }
    __builtin_amdgcn_s_setprio(1);
    acc[0][0] = MFMA16(af0, vb0, acc[0][0]);
    acc[1][0] = MFMA16(af1, vb0, acc[1][0]);
    acc[2][0] = MFMA16(af2, vb0, acc[2][0]);
    acc[3][0] = MFMA16(af3, vb0, acc[3][0]);
    acc[0][1] = MFMA16(af0, vb1, acc[0][1]);
    acc[1][1] = MFMA16(af1, vb1, acc[1][1]);
    acc[2][1] = MFMA16(af2, vb1, acc[2][1]);
    acc[3][1] = MFMA16(af3, vb1, acc[3][1]);
    __builtin_amdgcn_s_setprio(0);
    bf16x8 vb2 = *(const bf16x8*)&Sb[boff[2]];
    bf16x8 vb3 = *(const bf16x8*)&Sb[boff[3]];
    if (t < 30){ SB0_(b2, t+2); SB1_(b2, t+2); }
    __builtin_amdgcn_s_setprio(1);
    acc[0][2] = MFMA16(af0, vb2, acc[0][2]);
    acc[1][2] = MFMA16(af1, vb2, acc[1][2]);
    acc[2][2] = MFMA16(af2, vb2, acc[2][2]);
    acc[3][2] = MFMA16(af3, vb2, acc[3][2]);
    acc[0][3] = MFMA16(af0, vb3, acc[0][3]);
    acc[1][3] = MFMA16(af1, vb3, acc[1][3]);
    acc[2][3] = MFMA16(af2, vb3, acc[2][3]);
    acc[3][3] = MFMA16(af3, vb3, acc[3][3]);
    __builtin_amdgcn_s_setprio(0);
    int tmp = b0; b0 = b1; b1 = b2; b2 = tmp;
  }
#undef SA_
#undef SB0_
#undef SB1_

  #pragma unroll
  for (int mi = 0; mi < 4; mi++){
    int row = m0 + wm*64 + mi*16 + lg*4;
    #pragma unroll
    for (int ni = 0; ni < 4; ni++){
      int col = n0 + wn*64 + ni*16 + lr;
      f32x4 vv = acc[mi][ni];
      #pragma unroll
      for (int r = 0; r < 4; r++)
        fout[(size_t)(row + r)*1024 + col] = vv[r];
    }
  }
}

// ---------- causal flash attention: 4-wave blocks, KVBLK=64, K/V shared LDS dbuf ----------
// (r13 exact — best measured)
__global__ __launch_bounds__(256, 3) void k_attn(const u16* __restrict__ q, const u16* __restrict__ k2,
                                                 const u16* __restrict__ v2, u16* __restrict__ ctx){
  __shared__ u16 kv[2][8192];                 // per buf: K 8KB | V 8KB
  const int lane = threadIdx.x & 63, w = threadIdx.x >> 6;
  const int lq = lane & 31, hl = lane >> 5;
  const int B = blockIdx.x;
  const int bh = B & 63, g = 15 - (B >> 6);
  const int b = bh >> 4, h = bh & 15;
  const int qi = 4*g + w;
  const int q0 = qi * 32;
  const int qmax0 = (4*g + 3) * 32;           // block-uniform loop bound
  const u16* kglob = k2 + (size_t)bh*SEQ*64;
  const u16* vglob = v2 + (size_t)bh*(SEQ/16)*1024;

  const u16* qr_ = q + (size_t)(b*SEQ + q0 + lq)*D_MODEL + h*HEAD_DIM + hl*8;
  bf16x8 qf0 = *(const bf16x8*)&qr_[0];
  bf16x8 qf1 = *(const bf16x8*)&qr_[16];
  bf16x8 qf2 = *(const bf16x8*)&qr_[32];
  bf16x8 qf3 = *(const bf16x8*)&qr_[48];
  f32x16 acc0 = {}, acc1 = {};
  float m = -3.0e38f, l = 0.f;

  const int kr_ = (w<<3) + (lane>>3);                 // stage K row in 0..31
  const int kc_ = ((lane&7) ^ (lane>>3)) << 3;        // swizzled source chunk
  auto STAGE = [&](int bf, int jt){
    gload_lds16(kglob + (size_t)(jt      + kr_)*64 + kc_, &kv[bf][w<<9]);
    gload_lds16(kglob + (size_t)(jt + 32 + kr_)*64 + kc_, &kv[bf][2048 + (w<<9)]);
    gload_lds16(vglob + ((size_t)(jt>>4)<<10)        + (w<<9) + (lane<<3), &kv[bf][4096 + (w<<9)]);
    gload_lds16(vglob + ((size_t)((jt+32)>>4)<<10)   + (w<<9) + (lane<<3), &kv[bf][6144 + (w<<9)]);
  };

  STAGE(0, 0);
  __syncthreads();
  int p = 0;
  for (int j0 = 0; j0 <= qmax0; j0 += 64){
    if (j0 + 64 <= qmax0) STAGE(p^1, j0 + 64);
    if (j0 <= q0){
      const bool g2 = (j0 + 32 <= q0);
      const char* kb = (const char*)&kv[p][0];
      f32x16 S1 = {};
      {
        bf16x8 kf0 = *(const bf16x8*)(kb + lq*128 + (((0+hl) ^ (lq&7))<<4));
        bf16x8 kf1 = *(const bf16x8*)(kb + lq*128 + (((2+hl) ^ (lq&7))<<4));
        bf16x8 kf2 = *(const bf16x8*)(kb + lq*128 + (((4+hl) ^ (lq&7))<<4));
        bf16x8 kf3 = *(const bf16x8*)(kb + lq*128 + (((6+hl) ^ (lq&7))<<4));
        S1 = __builtin_amdgcn_mfma_f32_32x32x16_bf16(kf0, qf0, S1, 0, 0, 0);
        S1 = __builtin_amdgcn_mfma_f32_32x32x16_bf16(kf1, qf1, S1, 0, 0, 0);
        S1 = __builtin_amdgcn_mfma_f32_32x32x16_bf16(kf2, qf2, S1, 0, 0, 0);
        S1 = __builtin_amdgcn_mfma_f32_32x32x16_bf16(kf3, qf3, S1, 0, 0, 0);
      }
      if (j0 == q0){
        #pragma unroll
        for (int r = 0; r < 16; ++r){
          int kk = (r & 3) + 8*(r >> 2) + 4*hl;
          if (kk > lq) S1[r] = -3.0e38f;
        }
      }
      f32x16 S2 = {};
      if (g2){
        const char* kb2 = kb + 4096;
        bf16x8 kf0 = *(const bf16x8*)(kb2 + lq*128 + (((0+hl) ^ (lq&7))<<4));
        bf16x8 kf1 = *(const bf16x8*)(kb2 + lq*128 + (((2+hl) ^ (lq&7))<<4));
        bf16x8 kf2 = *(const bf16x8*)(kb2 + lq*128 + (((4+hl) ^ (lq&7))<<4));
        bf16x8 kf3 = *(const bf16x8*)(kb2 + lq*128 + (((6+hl) ^ (lq&7))<<4));
        S2 = __builtin_amdgcn_mfma_f32_32x32x16_bf16(kf0, qf0, S2, 0, 0, 0);
        S2 = __builtin_amdgcn_mfma_f32_32x32x16_bf16(kf1, qf1, S2, 0, 0, 0);
        S2 = __builtin_amdgcn_mfma_f32_32x32x16_bf16(kf2, qf2, S2, 0, 0, 0);
        S2 = __builtin_amdgcn_mfma_f32_32x32x16_bf16(kf3, qf3, S2, 0, 0, 0);
        if (j0 + 32 == q0){
          #pragma unroll
          for (int r = 0; r < 16; ++r){
            int kk = (r & 3) + 8*(r >> 2) + 4*hl;
            if (kk > lq) S2[r] = -3.0e38f;
          }
        }
      }
      float pm = fmaxf(fmaxf(fmaxf(S1[0],S1[1]), fmaxf(S1[2],S1[3])),
                       fmaxf(fmaxf(S1[4],S1[5]), fmaxf(S1[6],S1[7])));
      pm = fmaxf(pm, fmaxf(fmaxf(fmaxf(S1[8],S1[9]), fmaxf(S1[10],S1[11])),
                           fmaxf(fmaxf(S1[12],S1[13]),fmaxf(S1[14],S1[15]))));
      if (g2){
        float pm2 = fmaxf(fmaxf(fmaxf(S2[0],S2[1]), fmaxf(S2[2],S2[3])),
                          fmaxf(fmaxf(S2[4],S2[5]), fmaxf(S2[6],S2[7])));
        pm2 = fmaxf(pm2, fmaxf(fmaxf(fmaxf(S2[8],S2[9]), fmaxf(S2[10],S2[11])),
                               fmaxf(fmaxf(S2[12],S2[13]),fmaxf(S2[14],S2[15]))));
        pm = fmaxf(pm, pm2);
      }
      pm = fmaxf(pm, __shfl_xor(pm, 32));
      if (__any(pm > m + 8.f)){               // defer-max (T13)
        float mn = fmaxf(m, pm);
        float cr = __builtin_amdgcn_exp2f(m - mn);
        l *= cr;
        #pragma unroll
        for (int r = 0; r < 16; ++r){ acc0[r] *= cr; acc1[r] *= cr; }
        m = mn;
      }
      #pragma unroll
      for (int r = 0; r < 16; ++r) S1[r] = __builtin_amdgcn_exp2f(S1[r] - m);
      l += ((S1[0]+S1[1])+(S1[2]+S1[3])) + ((S1[4]+S1[5])+(S1[6]+S1[7]))
         + ((S1[8]+S1[9])+(S1[10]+S1[11])) + ((S1[12]+S1[13])+(S1[14]+S1[15]));
      {
        u32 g0a = cvtpk(S1[0], S1[1]),  g0b = cvtpk(S1[2], S1[3]);
        u32 g1a = cvtpk(S1[4], S1[5]),  g1b = cvtpk(S1[6], S1[7]);
        u32 g2a = cvtpk(S1[8], S1[9]),  g2b = cvtpk(S1[10],S1[11]);
        u32 g3a = cvtpk(S1[12],S1[13]), g3b = cvtpk(S1[14],S1[15]);
        u32 s0a = hl ? g0a : g1a, s0b = hl ? g0b : g1b;
        u32 e0a = (u32)__shfl_xor((int)s0a, 32), e0b = (u32)__shfl_xor((int)s0b, 32);
        u32 m0a = hl ? g1a : g0a, m0b = hl ? g1b : g0b;
        u32 s1a = hl ? g2a : g3a, s1b = hl ? g2b : g3b;
        u32 e1a = (u32)__shfl_xor((int)s1a, 32), e1b = (u32)__shfl_xor((int)s1b, 32);
        u32 m1a = hl ? g3a : g2a, m1b = hl ? g3b : g2b;
        u32x4 A0 = { hl ? e0a : m0a, hl ? e0b : m0b, hl ? m0a : e0a, hl ? m0b : e0b };
        u32x4 A1 = { hl ? e1a : m1a, hl ? e1b : m1b, hl ? m1a : e1a, hl ? m1b : e1b };
        bf16x8 pa0 = __builtin_bit_cast(bf16x8, A0);
        bf16x8 pa1 = __builtin_bit_cast(bf16x8, A1);
        const char* vb = kb + 8192;
        bf16x8 vf00 = *(const bf16x8*)(vb + lq*32 + hl*16);
        bf16x8 vf01 = *(const bf16x8*)(vb + lq*32 + hl*16 + 1024);
        bf16x8 vf10 = *(const bf16x8*)(vb + lq*32 + hl*16 + 2048);
        bf16x8 vf11 = *(const bf16x8*)(vb + lq*32 + hl*16 + 3072);
        acc0 = __builtin_amdgcn_mfma_f32_32x32x16_bf16(vf00, pa0, acc0, 0, 0, 0);
        acc0 = __builtin_amdgcn_mfma_f32_32x32x16_bf16(vf10, pa1, acc0, 0, 0, 0);
        acc1 = __builtin_amdgcn_mfma_f32_32x32x16_bf16(vf01, pa0, acc1, 0, 0, 0);
        acc1 = __builtin_amdgcn_mfma_f32_32x32x16_bf16(vf11, pa1, acc1, 0, 0, 0);
      }
      if (g2){
        #pragma unroll
        for (int r = 0; r < 16; ++r) S2[r] = __builtin_amdgcn_exp2f(S2[r] - m);
        l += ((S2[0]+S2[1])+(S2[2]+S2[3])) + ((S2[4]+S2[5])+(S2[6]+S2[7]))
           + ((S2[8]+S2[9])+(S2[10]+S2[11])) + ((S2[12]+S2[13])+(S2[14]+S2[15]));
        u32 g0a = cvtpk(S2[0], S2[1]),  g0b = cvtpk(S2[2], S2[3]);
        u32 g1a = cvtpk(S2[4], S2[5]),  g1b = cvtpk(S2[6], S2[7]);
        u32 g2a_ = cvtpk(S2[8], S2[9]), g2b_ = cvtpk(S2[10],S2[11]);
        u32 g3a = cvtpk(S2[12],S2[13]), g3b = cvtpk(S2[14],S2[15]);
        u32 s0a = hl ? g0a : g1a, s0b = hl ? g0b : g1b;
        u32 e0a = (u32)__shfl_xor((int)s0a, 32), e0b = (u32)__shfl_xor((int)s0b, 32);
        u32 m0a = hl ? g1a : g0a, m0b = hl ? g1b : g0b;
        u32 s1a = hl ? g2a_ : g3a, s1b = hl ? g2b_ : g3b;
        u32 e1a = (u32)__shfl_xor((int)s1a, 32), e1b = (u32)__shfl_xor((int)s1b, 32);
        u32 m1a = hl ? g3a : g2a_, m1b = hl ? g3b : g2b_;
        u32x4 A0 = { hl ? e0a : m0a, hl ? e0b : m0b, hl ? m0a : e0a, hl ? m0b : e0b };
        u32x4 A1 = { hl ? e1a : m1a, hl ? e1b : m1b, hl ? m1a : e1a, hl ? m1b : e1b };
        bf16x8 pa0 = __builtin_bit_cast(bf16x8, A0);
        bf16x8 pa1 = __builtin_bit_cast(bf16x8, A1);
        const char* vb = kb + 12288;
        bf16x8 vf00 = *(const bf16x8*)(vb + lq*32 + hl*16);
        bf16x8 vf01 = *(const bf16x8*)(vb + lq*32 + hl*16 + 1024);
        bf16x8 vf10 = *(const bf16x8*)(vb + lq*32 + hl*16 + 2048);
        bf16x8 vf11 = *(const bf16x8*)(vb + lq*32 + hl*16 + 3072);
        acc0 = __builtin_amdgcn_mfma_f32_32x32x16_bf16(vf00, pa0, acc0, 0, 0, 0);
        acc0 = __builtin_amdgcn_mfma_f32_32x32x16_bf16(vf10, pa1, acc0, 0, 0, 0);
        acc1 = __builtin_amdgcn_mfma_f32_32x32x16_bf16(vf01, pa0, acc1, 0, 0, 0);
        acc1 = __builtin_amdgcn_mfma_f32_32x32x16_bf16(vf11, pa1, acc1, 0, 0, 0);
      }
    }
    __syncthreads();
    p ^= 1;
  }
  l += __shfl_xor(l, 32);
  float inv = __builtin_amdgcn_rcpf(l);
  char* tbc = (char*)kv + w*4096;
  #pragma unroll
  for (int r = 0; r < 16; ++r){
    int d0 = (r & 3) + 8*(r >> 2) + 4*hl;
    *(u16*)(tbc + lq*128 + ((2*d0)      ^ ((lq & 7) << 4))) = f2bf(acc0[r] * inv);
    *(u16*)(tbc + lq*128 + ((2*(d0+32)) ^ ((lq & 7) << 4))) = f2bf(acc1[r] * inv);
  }
  int qr2 = lane >> 1, chb = (lane & 1) * 4;
  u16* cp = ctx + (size_t)(b*SEQ + q0 + qr2)*D_MODEL + h*HEAD_DIM;
  #pragma unroll
  for (int i = 0; i < 4; ++i){
    int ch = chb + i;
    u16x8 vv = *(const u16x8*)(tbc + qr2*128 + 16*(ch ^ (qr2 & 7)));
    *(u16x8*)&cp[ch*8] = vv;
  }
}

extern "C" void kernel_launch(void* const* d_in, const int* in_sizes, int n_in,
                              void* d_out, int out_size, void* d_ws, size_t ws_size,
                              hipStream_t stream){
  const float* x  = (const float*)d_in[0];
  const int*  pos = (const int*)d_in[1];
  const float* Wq = (const float*)d_in[2];
  const float* Wk = (const float*)d_in[3];
  const float* Wv = (const float*)d_in[4];
  const float* Wo = (const float*)d_in[5];
  float* out = (float*)d_out;
  char* ws = (char*)d_ws;
  u16* xb   = (u16*)(ws);                    // 16 MB  x bf16 (reused as ctx later)
  u16* wt   = (u16*)(ws + 16777216);         // 8 MB   Wt q,k,v,o transposed bf16 (q/k perm'd)
  u16* qb   = (u16*)(ws + 25165824);         // 16 MB  q row-major (roped, scaled, perm'd)
  u16* kbh  = (u16*)(ws + 41943040);         // 16 MB  k [b][h][s][64] (roped, perm'd)
  u16* vt2  = (u16*)(ws + 58720256);         // 16 MB  v [b][h][s/16][d][16]
  float2* tab = (float2*)(ws + 75497472);    // 512 KB rope table
  u16* ctxb = xb;

  k_prep<<<12544, 256, 0, stream>>>(x, Wq, Wk, Wv, Wo, pos, xb, wt, tab);
  k_gqkv<<<dim3(64,12), 512, 0, stream>>>(xb, wt, tab, qb, kbh, vt2);
  k_attn<<<dim3(1024), 256, 0, stream>>>(qb, kbh, vt2, ctxb);
  k_gwo2<<<dim3(64,4), 512, 0, stream>>>(ctxb, wt + 3145728, out);
}